// Round 7
// baseline (200.046 us; speedup 1.0000x reference)
//
#include <hip/hip_runtime.h>
#include <math.h>

// Problem constants: B,C,H,W = 32,64,64,64; K=1024
constexpr int Cc  = 64;
constexpr int Kc  = 1024;
constexpr int HW  = 4096;
constexpr int CHW = Cc * HW;          // 262144
constexpr int Nrows = 131072;
constexpr int TOTAL = 8388608;
constexpr int ROWS  = 64;             // rows per block
constexpr int NBLK  = Nrows / ROWS;   // 2048 blocks -> 8 blocks/CU

typedef __attribute__((ext_vector_type(8))) short short8;   // 8 bf16
typedef __attribute__((ext_vector_type(4))) float f32x4;

union U4S8 { uint4 u; short8 s; };

__device__ __forceinline__ unsigned bf16pair(float a, float b) {
    unsigned ua = __float_as_uint(a), ub = __float_as_uint(b);
    ua = (ua + 0x7FFFu + ((ua >> 16) & 1u)) >> 16;
    ub = (ub + 0x7FFFu + ((ub >> 16) & 1u)) & 0xFFFF0000u;
    return ua | ub;
}

__device__ __forceinline__ unsigned short bf16_rne(float x) {
    unsigned u = __float_as_uint(x);
    return (unsigned short)((u + 0x7FFFu + ((u >> 16) & 1u)) >> 16);
}

__device__ __forceinline__ unsigned umin3(unsigned a, unsigned b, unsigned c) {
    unsigned t = a < b ? a : b;           // compiler forms v_min3_u32
    return t < c ? t : c;
}

// ---------------------------------------------------------------------------
// Prep: e2p[k] = ||e_k||^2 (epilogue-only); codebook -> NEGATED bf16
// A-fragment order (so the scan's MFMA computes 0.5 - x.e with C=0.5):
//   cbA[(((ct*2+ks)*64) + quad*16 + n)*8 + j] = bf16(-cb[ct*16+n][ks*32+quad*8+j])
// Also zeroes counts.
// ---------------------------------------------------------------------------
__global__ void prep_kernel(const float* __restrict__ cb,
                            float* __restrict__ e2p,
                            unsigned short* __restrict__ cbA,
                            unsigned int* __restrict__ counts) {
    int k = blockIdx.x;          // code 0..1023
    int c = threadIdx.x;         // dim  0..63
    float v = cb[k * Cc + c];
    float s = v * v;
    #pragma unroll
    for (int off = 32; off; off >>= 1) s += __shfl_down(s, off);
    if (c == 0) {
        e2p[k] = s;
        counts[k] = 0u;
    }
    int ct = k >> 4, n = k & 15;
    int ks = c >> 5, quad = (c >> 3) & 3, j = c & 7;
    cbA[(((ct * 2 + ks) * 64) + quad * 16 + n) * 8 + j] = bf16_rne(-v);
}

// ---------------------------------------------------------------------------
// Main: 2048 blocks x 256 threads; block = 64 rows. Wave w owns ALL 64 rows
// as B-fragments (4 n-tiles, 32 VGPR) and streams its own 16 code tiles
// [w*16, +16) as A-fragments (disjoint quarter -> block reads the 128 KB
// bf16 codebook exactly once). MFMA C preloaded with 0.5 and codebook
// negated: acc = 0.5 - x.e in (0.4375, 0.5625) -> positive, uint order ==
// float order. Key: (bits(acc) & ~1023) | code; per-iter VALU is just
// and_or + min3. e2 (<=6e-5, below bf16-argmin noise) excluded from scan,
// re-added exactly in the epilogue. Cross-wave combine via 1 KB LDS table.
// ---------------------------------------------------------------------------
__global__ __launch_bounds__(256, 8) void vq_main(
        const float* __restrict__ inp,
        const float* __restrict__ cb,        // fp32 codebook (epilogue gather)
        const float* __restrict__ e2p,       // ||e||^2 (epilogue only)
        const uint4* __restrict__ cbA4,      // negated bf16 codebook, A-frag
        float* __restrict__ qout,
        unsigned int* __restrict__ counts,
        float* __restrict__ bsum) {          // per-block sse partial
    __shared__ uint4 lds_a[ROWS * 8];       // 8 KB: 64 rows x 8 chunks(16B)
    __shared__ unsigned lds_res[ROWS * 4];  // 1 KB: [row][wave]
    __shared__ float lds_x2w[4];

    const int tid = threadIdx.x;
    const int b   = blockIdx.x >> 6;        // 64 blocks per batch image
    const int hw0 = (blockIdx.x & 63) << 6; // 64 hw per block
    const int r   = tid & 63;               // row within block (== lane)
    const int w   = tid >> 6;
    const float* xp = inp + b * CHW + hw0 + r + w * 16 * HW;

    // ---- stage rows: wave w loads channels [w*16, w*16+16) of all 64 rows --
    float x2 = 0.f;
    {
        float v[16];
        #pragma unroll
        for (int j = 0; j < 16; ++j) {
            v[j] = __builtin_nontemporal_load(xp + j * HW);
            x2 = fmaf(v[j], v[j], x2);
        }
        uint4 p0, p1;
        p0.x = bf16pair(v[0],  v[1]);  p0.y = bf16pair(v[2],  v[3]);
        p0.z = bf16pair(v[4],  v[5]);  p0.w = bf16pair(v[6],  v[7]);
        p1.x = bf16pair(v[8],  v[9]);  p1.y = bf16pair(v[10], v[11]);
        p1.z = bf16pair(v[12], v[13]); p1.w = bf16pair(v[14], v[15]);
        lds_a[r * 8 + ((w * 2 + 0) ^ (r & 7))] = p0;
        lds_a[r * 8 + ((w * 2 + 1) ^ (r & 7))] = p1;
    }
    #pragma unroll
    for (int off = 32; off; off >>= 1) x2 += __shfl_down(x2, off);
    const int lane = tid & 63;
    if (lane == 0) lds_x2w[w] = x2;
    __syncthreads();

    const int col = lane & 15, quad = lane >> 4;

    // ---- resident B-fragments: ALL 64 rows (4 n-tiles) ----
    short8 bf[4][2];
    #pragma unroll
    for (int nt = 0; nt < 4; ++nt) {
        int row = nt * 16 + col;
        #pragma unroll
        for (int ks = 0; ks < 2; ++ks) {
            U4S8 t; t.u = lds_a[row * 8 + ((ks * 4 + quad) ^ (row & 7))];
            bf[nt][ks] = t.s;
        }
    }

    unsigned best[4];
    #pragma unroll
    for (int nt = 0; nt < 4; ++nt) best[nt] = 0xFFFFFFFFu;

    unsigned c0 = (unsigned)(w * 256 + quad * 4);
    unsigned c1 = c0 + 1, c2 = c0 + 2, c3 = c0 + 3;

    // ---- stream this wave's 16 code tiles, prefetch depth 2 ----
    const uint4* pc = cbA4 + (w * 16) * 128;    // wave's quarter of the book
    uint4 pa0[2], pa1[2];
    pa0[0] = pc[lane];        pa1[0] = pc[64 + lane];
    pa0[1] = pc[128 + lane];  pa1[1] = pc[192 + lane];
    #pragma unroll 2
    for (int i = 0; i < 16; ++i) {
        U4S8 t0, t1; t0.u = pa0[i & 1]; t1.u = pa1[i & 1];
        int ni = (i + 2) & 15;               // wave-uniform wrap (scalar ALU)
        pa0[i & 1] = pc[ni * 128 + lane];
        pa1[i & 1] = pc[ni * 128 + 64 + lane];

        #pragma unroll
        for (int nt = 0; nt < 4; ++nt) {
            f32x4 acc = {0.5f, 0.5f, 0.5f, 0.5f};
            acc = __builtin_amdgcn_mfma_f32_16x16x32_bf16(t0.s, bf[nt][0], acc, 0, 0, 0);
            acc = __builtin_amdgcn_mfma_f32_16x16x32_bf16(t1.s, bf[nt][1], acc, 0, 0, 0);
            unsigned k0 = (__float_as_uint(acc[0]) & 0xFFFFFC00u) | c0;
            unsigned k1 = (__float_as_uint(acc[1]) & 0xFFFFFC00u) | c1;
            unsigned k2 = (__float_as_uint(acc[2]) & 0xFFFFFC00u) | c2;
            unsigned k3 = (__float_as_uint(acc[3]) & 0xFFFFFC00u) | c3;
            best[nt] = umin3(best[nt], k0, k1);
            best[nt] = umin3(best[nt], k2, k3);
        }
        c0 += 16; c1 += 16; c2 += 16; c3 += 16;
    }

    // ---- reduce over the 4 quads (codes); lane col posts row nt*16+col ----
    #pragma unroll
    for (int nt = 0; nt < 4; ++nt) {
        unsigned v = best[nt];
        unsigned o = (unsigned)__shfl_xor((int)v, 16); v = v < o ? v : o;
        o = (unsigned)__shfl_xor((int)v, 32);          v = v < o ? v : o;
        if (quad == 0) lds_res[(nt * 16 + col) * 4 + w] = v;
    }
    __syncthreads();

    // ---- epilogue: combine the four code-quarters per row ----
    uint4 cand = *reinterpret_cast<const uint4*>(&lds_res[r * 4]);
    unsigned va = cand.x < cand.y ? cand.x : cand.y;
    unsigned vb = cand.z < cand.w ? cand.z : cand.w;
    unsigned vres = va < vb ? va : vb;
    int idx = (int)(vres & 1023u);

    // q_out gather/store: thread (r, w) writes channels [w*16, +16) of row r
    const float4* qv = reinterpret_cast<const float4*>(cb + idx * Cc) + w * 4;
    float* op = qout + b * CHW + hw0 + r + w * 16 * HW;
    #pragma unroll
    for (int j = 0; j < 4; ++j) {
        float4 qq = qv[j];
        __builtin_nontemporal_store(qq.x, op + (j * 4 + 0) * HW);
        __builtin_nontemporal_store(qq.y, op + (j * 4 + 1) * HW);
        __builtin_nontemporal_store(qq.z, op + (j * 4 + 2) * HW);
        __builtin_nontemporal_store(qq.w, op + (j * 4 + 3) * HW);
    }

    if (tid < 64) {                          // wave 0: one lane per row
        // d' = 0.5 - x.e  ->  ||x-e||^2 = x2 + 2d' - 1 + ||e||^2
        float dq = __uint_as_float(vres & 0xFFFFFC00u);
        float se = fmaf(2.0f, dq, e2p[idx] - 1.0f);
        atomicAdd(&counts[idx], 1u);
        #pragma unroll
        for (int off = 32; off; off >>= 1) se += __shfl_down(se, off);
        if (lane == 0) {
            float x2b = lds_x2w[0] + lds_x2w[1] + lds_x2w[2] + lds_x2w[3];
            bsum[blockIdx.x] = se + x2b;     // block's sum of ||x-e||^2
        }
    }
}

// ---------------------------------------------------------------------------
__global__ void finalize_kernel(const unsigned int* __restrict__ counts,
                                const float* __restrict__ bsum,
                                const float* __restrict__ beta,
                                float* __restrict__ loss_out,
                                float* __restrict__ perp_out) {
    __shared__ float redp[16], reds[16];
    int t = threadIdx.x;                  // 0..1023 == K
    float p = (float)counts[t] * (1.0f / (float)Nrows);
    float sp = p * logf(p + 1e-10f);
    float ss = bsum[t] + bsum[t + 1024];
    #pragma unroll
    for (int off = 32; off; off >>= 1) {
        sp += __shfl_down(sp, off);
        ss += __shfl_down(ss, off);
    }
    if ((t & 63) == 0) { redp[t >> 6] = sp; reds[t >> 6] = ss; }
    __syncthreads();
    if (t == 0) {
        float tp = 0.f, ts = 0.f;
        #pragma unroll
        for (int i = 0; i < 16; ++i) { tp += redp[i]; ts += reds[i]; }
        *perp_out = expf(-tp);
        *loss_out = (1.0f + *beta) * ts * (1.0f / (float)TOTAL);
    }
}

// ---------------------------------------------------------------------------
// Workspace layout (bytes):
//   [0, 4096)        counts (1024 u32)   -- zeroed by prep
//   [4096, 8192)     e2p (1024 f32)
//   [8192, 16384)    bsum (2048 f32)     -- fully written by vq_main
//   [16384, 147456)  cbA negated bf16 A-frag order (64 tiles x 2 KB)
// ---------------------------------------------------------------------------
extern "C" void kernel_launch(void* const* d_in, const int* in_sizes, int n_in,
                              void* d_out, int out_size, void* d_ws, size_t ws_size,
                              hipStream_t stream) {
    const float* inp  = (const float*)d_in[0];
    const float* cb   = (const float*)d_in[1];
    const float* beta = (const float*)d_in[2];

    float* loss = (float*)d_out;
    float* qout = loss + 1;
    float* perp = loss + 1 + TOTAL;

    char* ws = (char*)d_ws;
    unsigned int* counts = (unsigned int*)ws;
    float* e2p  = (float*)(ws + 4096);
    float* bsum = (float*)(ws + 8192);
    unsigned short* cbA = (unsigned short*)(ws + 16384);

    prep_kernel<<<Kc, 64, 0, stream>>>(cb, e2p, cbA, counts);
    vq_main<<<NBLK, 256, 0, stream>>>(inp, cb, e2p, (const uint4*)cbA,
                                      qout, counts, bsum);
    finalize_kernel<<<1, Kc, 0, stream>>>(counts, bsum, beta, loss, perp);
}

// Round 8
// 121.295 us; speedup vs baseline: 1.6493x; 1.6493x over previous
//
#include <hip/hip_runtime.h>
#include <math.h>

// Problem constants: B,C,H,W = 32,64,64,64; K=1024
constexpr int Cc  = 64;
constexpr int Kc  = 1024;
constexpr int HW  = 4096;
constexpr int CHW = Cc * HW;          // 262144
constexpr int Nrows = 131072;
constexpr int TOTAL = 8388608;
constexpr int ROWS  = 64;             // rows per block
constexpr int NBLK  = Nrows / ROWS;   // 2048 blocks -> 8 blocks/CU

typedef __attribute__((ext_vector_type(8))) short short8;   // 8 bf16
typedef __attribute__((ext_vector_type(4))) float f32x4;

union U4S8 { uint4 u; short8 s; };

__device__ __forceinline__ unsigned bf16pair(float a, float b) {
    unsigned ua = __float_as_uint(a), ub = __float_as_uint(b);
    ua = (ua + 0x7FFFu + ((ua >> 16) & 1u)) >> 16;
    ub = (ub + 0x7FFFu + ((ub >> 16) & 1u)) & 0xFFFF0000u;
    return ua | ub;
}

__device__ __forceinline__ unsigned short bf16_rne(float x) {
    unsigned u = __float_as_uint(x);
    return (unsigned short)((u + 0x7FFFu + ((u >> 16) & 1u)) >> 16);
}

__device__ __forceinline__ unsigned umin3(unsigned a, unsigned b, unsigned c) {
    unsigned t = a < b ? a : b;           // compiler forms v_min3_u32
    return t < c ? t : c;
}

// ---------------------------------------------------------------------------
// Prep: e2p[k] = ||e_k||^2 (epilogue-only); codebook -> NEGATED bf16
// A-fragment order (so the scan's MFMA computes 0.5 - x.e with C=0.5):
//   cbA[(((ct*2+ks)*64) + quad*16 + n)*8 + j] = bf16(-cb[ct*16+n][ks*32+quad*8+j])
// Also zeroes counts.
// ---------------------------------------------------------------------------
__global__ void prep_kernel(const float* __restrict__ cb,
                            float* __restrict__ e2p,
                            unsigned short* __restrict__ cbA,
                            unsigned int* __restrict__ counts) {
    int k = blockIdx.x;          // code 0..1023
    int c = threadIdx.x;         // dim  0..63
    float v = cb[k * Cc + c];
    float s = v * v;
    #pragma unroll
    for (int off = 32; off; off >>= 1) s += __shfl_down(s, off);
    if (c == 0) {
        e2p[k] = s;
        counts[k] = 0u;
    }
    int ct = k >> 4, n = k & 15;
    int ks = c >> 5, quad = (c >> 3) & 3, j = c & 7;
    cbA[(((ct * 2 + ks) * 64) + quad * 16 + n) * 8 + j] = bf16_rne(-v);
}

// ---------------------------------------------------------------------------
// Main: 2048 blocks x 256 threads; block = 64 rows. Wave w owns ALL 64 rows
// as B-fragments (4 n-tiles, 32 VGPR) and streams its own 16 code tiles
// [w*16, +16) as A-fragments (disjoint quarter -> block reads the 128 KB
// bf16 codebook exactly once). launch_bounds(256,4): 128 regs/wave so the
// ~74-reg live set does NOT spill (R7's launch_bounds(256,8) spilled ~70
// dwords/thread -> 160 MB of scratch traffic -> 2.7x regression).
// MFMA C preloaded with 0.5, codebook negated: acc = 0.5 - x.e in
// (0.4375, 0.5625) -> positive, uint order == float order.
// Key: (bits(acc) & ~1023) | code. e2 (<=6e-5, below bf16-argmin noise)
// excluded from scan, re-added exactly in epilogue. Cross-wave combine via
// 1 KB LDS table.
// ---------------------------------------------------------------------------
__global__ __launch_bounds__(256, 4) void vq_main(
        const float* __restrict__ inp,
        const float* __restrict__ cb,        // fp32 codebook (epilogue gather)
        const float* __restrict__ e2p,       // ||e||^2 (epilogue only)
        const uint4* __restrict__ cbA4,      // negated bf16 codebook, A-frag
        float* __restrict__ qout,
        unsigned int* __restrict__ counts,
        float* __restrict__ bsum) {          // per-block sse partial
    __shared__ uint4 lds_a[ROWS * 8];       // 8 KB: 64 rows x 8 chunks(16B)
    __shared__ unsigned lds_res[ROWS * 4];  // 1 KB: [row][wave]
    __shared__ float lds_x2w[4];

    const int tid = threadIdx.x;
    const int b   = blockIdx.x >> 6;        // 64 blocks per batch image
    const int hw0 = (blockIdx.x & 63) << 6; // 64 hw per block
    const int r   = tid & 63;               // row within block (== lane)
    const int w   = tid >> 6;
    const float* xp = inp + b * CHW + hw0 + r + w * 16 * HW;

    // ---- stage rows: wave w loads channels [w*16, w*16+16) of all 64 rows --
    // (plain loads: input is L3-resident across replays; keep it cached)
    float x2 = 0.f;
    {
        float v[16];
        #pragma unroll
        for (int j = 0; j < 16; ++j) {
            v[j] = xp[j * HW];
            x2 = fmaf(v[j], v[j], x2);
        }
        uint4 p0, p1;
        p0.x = bf16pair(v[0],  v[1]);  p0.y = bf16pair(v[2],  v[3]);
        p0.z = bf16pair(v[4],  v[5]);  p0.w = bf16pair(v[6],  v[7]);
        p1.x = bf16pair(v[8],  v[9]);  p1.y = bf16pair(v[10], v[11]);
        p1.z = bf16pair(v[12], v[13]); p1.w = bf16pair(v[14], v[15]);
        lds_a[r * 8 + ((w * 2 + 0) ^ (r & 7))] = p0;
        lds_a[r * 8 + ((w * 2 + 1) ^ (r & 7))] = p1;
    }
    #pragma unroll
    for (int off = 32; off; off >>= 1) x2 += __shfl_down(x2, off);
    const int lane = tid & 63;
    if (lane == 0) lds_x2w[w] = x2;
    __syncthreads();

    const int col = lane & 15, quad = lane >> 4;

    // ---- resident B-fragments: ALL 64 rows (4 n-tiles, 32 VGPR) ----
    short8 bf[4][2];
    #pragma unroll
    for (int nt = 0; nt < 4; ++nt) {
        int row = nt * 16 + col;
        #pragma unroll
        for (int ks = 0; ks < 2; ++ks) {
            U4S8 t; t.u = lds_a[row * 8 + ((ks * 4 + quad) ^ (row & 7))];
            bf[nt][ks] = t.s;
        }
    }

    unsigned best[4];
    #pragma unroll
    for (int nt = 0; nt < 4; ++nt) best[nt] = 0xFFFFFFFFu;

    unsigned c0 = (unsigned)(w * 256 + quad * 4);
    unsigned c1 = c0 + 1, c2 = c0 + 2, c3 = c0 + 3;

    // ---- stream this wave's 16 code tiles, prefetch depth 2 ----
    const uint4* pc = cbA4 + (w * 16) * 128;    // wave's quarter of the book
    uint4 pa0[2], pa1[2];
    pa0[0] = pc[lane];        pa1[0] = pc[64 + lane];
    pa0[1] = pc[128 + lane];  pa1[1] = pc[192 + lane];
    #pragma unroll 2
    for (int i = 0; i < 16; ++i) {
        U4S8 t0, t1; t0.u = pa0[i & 1]; t1.u = pa1[i & 1];
        int ni = (i + 2) & 15;               // wave-uniform wrap (scalar ALU)
        pa0[i & 1] = pc[ni * 128 + lane];
        pa1[i & 1] = pc[ni * 128 + 64 + lane];

        #pragma unroll
        for (int nt = 0; nt < 4; ++nt) {
            f32x4 acc = {0.5f, 0.5f, 0.5f, 0.5f};
            acc = __builtin_amdgcn_mfma_f32_16x16x32_bf16(t0.s, bf[nt][0], acc, 0, 0, 0);
            acc = __builtin_amdgcn_mfma_f32_16x16x32_bf16(t1.s, bf[nt][1], acc, 0, 0, 0);
            unsigned k0 = (__float_as_uint(acc[0]) & 0xFFFFFC00u) | c0;
            unsigned k1 = (__float_as_uint(acc[1]) & 0xFFFFFC00u) | c1;
            unsigned k2 = (__float_as_uint(acc[2]) & 0xFFFFFC00u) | c2;
            unsigned k3 = (__float_as_uint(acc[3]) & 0xFFFFFC00u) | c3;
            best[nt] = umin3(best[nt], k0, k1);
            best[nt] = umin3(best[nt], k2, k3);
        }
        c0 += 16; c1 += 16; c2 += 16; c3 += 16;
    }

    // ---- reduce over the 4 quads (codes); lane col posts row nt*16+col ----
    #pragma unroll
    for (int nt = 0; nt < 4; ++nt) {
        unsigned v = best[nt];
        unsigned o = (unsigned)__shfl_xor((int)v, 16); v = v < o ? v : o;
        o = (unsigned)__shfl_xor((int)v, 32);          v = v < o ? v : o;
        if (quad == 0) lds_res[(nt * 16 + col) * 4 + w] = v;
    }
    __syncthreads();

    // ---- epilogue: combine the four code-quarters per row ----
    uint4 cand = *reinterpret_cast<const uint4*>(&lds_res[r * 4]);
    unsigned va = cand.x < cand.y ? cand.x : cand.y;
    unsigned vb = cand.z < cand.w ? cand.z : cand.w;
    unsigned vres = va < vb ? va : vb;
    int idx = (int)(vres & 1023u);

    // q_out gather/store: thread (r, w) writes channels [w*16, +16) of row r
    const float4* qv = reinterpret_cast<const float4*>(cb + idx * Cc) + w * 4;
    float* op = qout + b * CHW + hw0 + r + w * 16 * HW;
    #pragma unroll
    for (int j = 0; j < 4; ++j) {
        float4 qq = qv[j];
        __builtin_nontemporal_store(qq.x, op + (j * 4 + 0) * HW);
        __builtin_nontemporal_store(qq.y, op + (j * 4 + 1) * HW);
        __builtin_nontemporal_store(qq.z, op + (j * 4 + 2) * HW);
        __builtin_nontemporal_store(qq.w, op + (j * 4 + 3) * HW);
    }

    if (tid < 64) {                          // wave 0: one lane per row
        // d' = 0.5 - x.e  ->  ||x-e||^2 = x2 + 2d' - 1 + ||e||^2
        float dq = __uint_as_float(vres & 0xFFFFFC00u);
        float se = fmaf(2.0f, dq, e2p[idx] - 1.0f);
        atomicAdd(&counts[idx], 1u);
        #pragma unroll
        for (int off = 32; off; off >>= 1) se += __shfl_down(se, off);
        if (lane == 0) {
            float x2b = lds_x2w[0] + lds_x2w[1] + lds_x2w[2] + lds_x2w[3];
            bsum[blockIdx.x] = se + x2b;     // block's sum of ||x-e||^2
        }
    }
}

// ---------------------------------------------------------------------------
__global__ void finalize_kernel(const unsigned int* __restrict__ counts,
                                const float* __restrict__ bsum,
                                const float* __restrict__ beta,
                                float* __restrict__ loss_out,
                                float* __restrict__ perp_out) {
    __shared__ float redp[16], reds[16];
    int t = threadIdx.x;                  // 0..1023 == K
    float p = (float)counts[t] * (1.0f / (float)Nrows);
    float sp = p * logf(p + 1e-10f);
    float ss = bsum[t] + bsum[t + 1024];
    #pragma unroll
    for (int off = 32; off; off >>= 1) {
        sp += __shfl_down(sp, off);
        ss += __shfl_down(ss, off);
    }
    if ((t & 63) == 0) { redp[t >> 6] = sp; reds[t >> 6] = ss; }
    __syncthreads();
    if (t == 0) {
        float tp = 0.f, ts = 0.f;
        #pragma unroll
        for (int i = 0; i < 16; ++i) { tp += redp[i]; ts += reds[i]; }
        *perp_out = expf(-tp);
        *loss_out = (1.0f + *beta) * ts * (1.0f / (float)TOTAL);
    }
}

// ---------------------------------------------------------------------------
// Workspace layout (bytes):
//   [0, 4096)        counts (1024 u32)   -- zeroed by prep
//   [4096, 8192)     e2p (1024 f32)
//   [8192, 16384)    bsum (2048 f32)     -- fully written by vq_main
//   [16384, 147456)  cbA negated bf16 A-frag order (64 tiles x 2 KB)
// ---------------------------------------------------------------------------
extern "C" void kernel_launch(void* const* d_in, const int* in_sizes, int n_in,
                              void* d_out, int out_size, void* d_ws, size_t ws_size,
                              hipStream_t stream) {
    const float* inp  = (const float*)d_in[0];
    const float* cb   = (const float*)d_in[1];
    const float* beta = (const float*)d_in[2];

    float* loss = (float*)d_out;
    float* qout = loss + 1;
    float* perp = loss + 1 + TOTAL;

    char* ws = (char*)d_ws;
    unsigned int* counts = (unsigned int*)ws;
    float* e2p  = (float*)(ws + 4096);
    float* bsum = (float*)(ws + 8192);
    unsigned short* cbA = (unsigned short*)(ws + 16384);

    prep_kernel<<<Kc, 64, 0, stream>>>(cb, e2p, cbA, counts);
    vq_main<<<NBLK, 256, 0, stream>>>(inp, cb, e2p, (const uint4*)cbA,
                                      qout, counts, bsum);
    finalize_kernel<<<1, Kc, 0, stream>>>(counts, bsum, beta, loss, perp);
}